// Round 4
// baseline (319.827 us; speedup 1.0000x reference)
//
#include <hip/hip_runtime.h>
#include <hip/hip_bf16.h>

typedef __attribute__((ext_vector_type(8))) short short8;
typedef __attribute__((ext_vector_type(4))) float f32x4;

static constexpr int MT = 32768;  // rows
static constexpr int KT = 256;    // contraction
static constexpr int CT = 4096;   // classes

// round-to-nearest-even float -> bf16 bits
__device__ __forceinline__ unsigned short f2b(float f) {
  unsigned int b = __float_as_uint(f);
  b += 0x7FFFu + ((b >> 16) & 1u);
  return (unsigned short)(b >> 16);
}

__global__ void __launch_bounds__(256) cvtA_kernel(const float* __restrict__ A,
                                                   unsigned short* __restrict__ Abf) {
  int i = blockIdx.x * 256 + threadIdx.x;  // 8 floats per lane
  const float4 v0 = reinterpret_cast<const float4*>(A)[2 * i];
  const float4 v1 = reinterpret_cast<const float4*>(A)[2 * i + 1];
  short8 o;
  o[0] = (short)f2b(v0.x); o[1] = (short)f2b(v0.y);
  o[2] = (short)f2b(v0.z); o[3] = (short)f2b(v0.w);
  o[4] = (short)f2b(v1.x); o[5] = (short)f2b(v1.y);
  o[6] = (short)f2b(v1.z); o[7] = (short)f2b(v1.w);
  reinterpret_cast<short8*>(Abf)[i] = o;
}

// B [KT][CT] fp32 -> Bt [CT][KT] bf16 (LDS-tiled transpose)
__global__ void __launch_bounds__(1024) cvtB_kernel(const float* __restrict__ B,
                                                    unsigned short* __restrict__ Bt) {
  __shared__ unsigned short tile[32][33];
  int tx = threadIdx.x & 31, ty = threadIdx.x >> 5;
  int c0 = blockIdx.x * 32, k0 = blockIdx.y * 32;
  tile[ty][tx] = f2b(B[(size_t)(k0 + ty) * CT + c0 + tx]);
  __syncthreads();
  Bt[(size_t)(c0 + ty) * KT + k0 + tx] = tile[tx][ty];
}

// LDS-free GEMM: B (2 MB bf16) is fully L2-resident, A panels stream through
// L2/L3; fragments load straight from global into registers. No barriers.
__global__ void __launch_bounds__(256) gemm_kernel(const unsigned short* __restrict__ Abf,
                                                   const unsigned short* __restrict__ Btw,
                                                   float* __restrict__ O) {
  int bid = blockIdx.x;
  // XCD-aware swizzle; 8192 % 8 == 0 so the simple form is bijective.
  // Each XCD gets 32 consecutive row-panels: A working set 2MB + B 2MB ~ L2.
  int wg = (bid & 7) * 1024 + (bid >> 3);
  int tc = wg & 31;   // 32 col tiles
  int tr = wg >> 5;   // 256 row tiles
  int r0 = tr * 128, c0 = tc * 128;

  int tid = threadIdx.x;
  int lane = tid & 63, wid = tid >> 6;
  int wr = wid >> 1, wc = wid & 1;      // 2x2 waves, each owns 64x64
  int l15 = lane & 15, l4 = lane >> 4;

  // Per-lane fragment base pointers (computed once; K advances by immediate).
  const unsigned short* pa[4];
  const unsigned short* pb[4];
#pragma unroll
  for (int m = 0; m < 4; ++m)
    pa[m] = Abf + (size_t)(r0 + wr * 64 + m * 16 + l15) * KT + l4 * 8;
#pragma unroll
  for (int n = 0; n < 4; ++n)
    pb[n] = Btw + (size_t)(c0 + wc * 64 + n * 16 + l15) * KT + l4 * 8;

  f32x4 acc[4][4] = {};          // acc[n][m], swapped-operand orientation
  short8 af[2][4], bf[2][4];     // register double-buffer (static idx via unroll)

#pragma unroll
  for (int m = 0; m < 4; ++m) af[0][m] = *reinterpret_cast<const short8*>(pa[m]);
#pragma unroll
  for (int n = 0; n < 4; ++n) bf[0][n] = *reinterpret_cast<const short8*>(pb[n]);

#pragma unroll
  for (int t = 0; t < 8; ++t) {      // K = 8 x 32
    const int cur = t & 1, nxt = cur ^ 1;
    if (t < 7) {
#pragma unroll
      for (int m = 0; m < 4; ++m)
        af[nxt][m] = *reinterpret_cast<const short8*>(pa[m] + (t + 1) * 32);
#pragma unroll
      for (int n = 0; n < 4; ++n)
        bf[nxt][n] = *reinterpret_cast<const short8*>(pb[n] + (t + 1) * 32);
    }
#pragma unroll
    for (int n = 0; n < 4; ++n)
#pragma unroll
      for (int m = 0; m < 4; ++m)
        // swapped operands: lane holds 4 consecutive C columns of one row
        acc[n][m] = __builtin_amdgcn_mfma_f32_16x16x32_bf16(bf[cur][n], af[cur][m],
                                                            acc[n][m], 0, 0, 0);
  }

  // Epilogue: dwordx4 stores, 16 rows x 64B segments per instruction.
  const float s = 1.0f / 16.0f;
#pragma unroll
  for (int n = 0; n < 4; ++n)
#pragma unroll
    for (int m = 0; m < 4; ++m) {
      f32x4 v = acc[n][m];
      v[0] *= s; v[1] *= s; v[2] *= s; v[3] *= s;
      size_t off = (size_t)(r0 + wr * 64 + m * 16 + l15) * CT +
                   (c0 + wc * 64 + n * 16 + l4 * 4);
      *reinterpret_cast<f32x4*>(O + off) = v;
    }
}

// Correct-but-slow insurance path if ws_size is too small for the bf16 copies.
__global__ void __launch_bounds__(256) naive_kernel(const float* __restrict__ A,
                                                    const float* __restrict__ B,
                                                    float* __restrict__ O) {
  size_t i = (size_t)blockIdx.x * 256 + threadIdx.x;
  int col = (int)(i & (size_t)(CT - 1));
  int row = (int)(i >> 12);
  float s = 0.f;
  for (int k = 0; k < KT; ++k)
    s += A[(size_t)row * KT + k] * B[(size_t)k * CT + col];
  O[i] = s * (1.0f / 16.0f);
}

extern "C" void kernel_launch(void* const* d_in, const int* in_sizes, int n_in,
                              void* d_out, int out_size, void* d_ws, size_t ws_size,
                              hipStream_t stream) {
  const float* A = (const float*)d_in[0];
  const float* B = (const float*)d_in[1];
  float* O = (float*)d_out;
  const size_t needA = (size_t)MT * KT * sizeof(unsigned short);  // 16 MiB
  const size_t needB = (size_t)CT * KT * sizeof(unsigned short);  //  2 MiB
  if (ws_size >= needA + needB) {
    unsigned short* Abf = (unsigned short*)d_ws;
    unsigned short* Btw = (unsigned short*)((char*)d_ws + needA);
    cvtA_kernel<<<MT * KT / 8 / 256, 256, 0, stream>>>(A, Abf);
    cvtB_kernel<<<dim3(CT / 32, KT / 32), 1024, 0, stream>>>(B, Btw);
    gemm_kernel<<<(MT / 128) * (CT / 128), 256, 0, stream>>>(Abf, Btw, O);
  } else {
    naive_kernel<<<(unsigned)((size_t)MT * CT / 256), 256, 0, stream>>>(A, B, O);
  }
}

// Round 5
// 153.915 us; speedup vs baseline: 2.0779x; 2.0779x over previous
//
#include <hip/hip_runtime.h>
#include <hip/hip_bf16.h>

typedef __attribute__((ext_vector_type(8))) short short8;
typedef __attribute__((ext_vector_type(4))) float f32x4;

static constexpr int MT = 32768;  // rows
static constexpr int KT = 256;    // contraction
static constexpr int CT = 4096;   // classes

// round-to-nearest-even float -> bf16 bits
__device__ __forceinline__ unsigned short f2b(float f) {
  unsigned int b = __float_as_uint(f);
  b += 0x7FFFu + ((b >> 16) & 1u);
  return (unsigned short)(b >> 16);
}

__global__ void __launch_bounds__(256) cvtA_kernel(const float* __restrict__ A,
                                                   unsigned short* __restrict__ Abf) {
  int i = blockIdx.x * 256 + threadIdx.x;  // 8 floats per lane
  const float4 v0 = reinterpret_cast<const float4*>(A)[2 * i];
  const float4 v1 = reinterpret_cast<const float4*>(A)[2 * i + 1];
  short8 o;
  o[0] = (short)f2b(v0.x); o[1] = (short)f2b(v0.y);
  o[2] = (short)f2b(v0.z); o[3] = (short)f2b(v0.w);
  o[4] = (short)f2b(v1.x); o[5] = (short)f2b(v1.y);
  o[6] = (short)f2b(v1.z); o[7] = (short)f2b(v1.w);
  reinterpret_cast<short8*>(Abf)[i] = o;
}

// B [KT][CT] fp32 -> Bt [CT][KT] bf16 (LDS-tiled transpose)
__global__ void __launch_bounds__(1024) cvtB_kernel(const float* __restrict__ B,
                                                    unsigned short* __restrict__ Bt) {
  __shared__ unsigned short tile[32][33];
  int tx = threadIdx.x & 31, ty = threadIdx.x >> 5;
  int c0 = blockIdx.x * 32, k0 = blockIdx.y * 32;
  tile[ty][tx] = f2b(B[(size_t)(k0 + ty) * CT + c0 + tx]);
  __syncthreads();
  Bt[(size_t)(c0 + ty) * KT + k0 + tx] = tile[tx][ty];
}

__device__ __forceinline__ void gload16(const void* g, void* l) {
  __builtin_amdgcn_global_load_lds(
      (const __attribute__((address_space(1))) void*)g,
      (__attribute__((address_space(3))) void*)l, 16, 0, 0);
}

__global__ void __launch_bounds__(256) gemm_kernel(const unsigned short* __restrict__ Abf,
                                                   const unsigned short* __restrict__ Btw,
                                                   float* __restrict__ O) {
  constexpr int BM = 128, BN = 128, BK = 32;
  __shared__ __align__(16) unsigned short Al[BM * BK];  // [m][k], 8 KB
  __shared__ __align__(16) unsigned short Bl[BN * BK];  // [c][k], 8 KB

  int bid = blockIdx.x;
  // XCD-aware swizzle; 8192 % 8 == 0 so the simple form is bijective
  int wg = (bid & 7) * (8192 / 8) + (bid >> 3);
  int tc = wg & 31;   // 32 col tiles
  int tr = wg >> 5;   // 256 row tiles
  int r0 = tr * BM, c0 = tc * BN;

  int tid = threadIdx.x;
  int lane = tid & 63, wid = tid >> 6;
  int wr = wid >> 1, wc = wid & 1;      // 2x2 waves, each owns 64x64
  int l15 = lane & 15, l4 = lane >> 4;

  f32x4 acc[4][4] = {};  // acc[n][m], swapped-operand orientation

  const int rowA = tid >> 2;            // 0..63 within a 64-row half
  const int kofs = (tid & 3) * 8;       // ushort offset within 32-wide K slab

  for (int t = 0; t < KT / BK; ++t) {
    if (t) __syncthreads();
#pragma unroll
    for (int j = 0; j < 2; ++j) {
      gload16(Abf + (size_t)(r0 + j * 64 + rowA) * KT + t * BK + kofs,
              Al + j * 2048 + wid * 512);
      gload16(Btw + (size_t)(c0 + j * 64 + rowA) * KT + t * BK + kofs,
              Bl + j * 2048 + wid * 512);
    }
    __syncthreads();  // drains vmcnt before barrier

    short8 af[4], bf[4];
#pragma unroll
    for (int m = 0; m < 4; ++m)
      af[m] = *reinterpret_cast<const short8*>(Al + (wr * 64 + m * 16 + l15) * BK + l4 * 8);
#pragma unroll
    for (int n = 0; n < 4; ++n)
      bf[n] = *reinterpret_cast<const short8*>(Bl + (wc * 64 + n * 16 + l15) * BK + l4 * 8);
#pragma unroll
    for (int n = 0; n < 4; ++n)
#pragma unroll
      for (int m = 0; m < 4; ++m)
        // swapped operands: lane holds 4 consecutive C columns of one row
        acc[n][m] = __builtin_amdgcn_mfma_f32_16x16x32_bf16(bf[n], af[m], acc[n][m], 0, 0, 0);
  }

  // Epilogue: dwordx4 NON-TEMPORAL stores — output is never re-read; bypass
  // L2 so A/B panels stay resident for the staging reads of other blocks.
  const float s = 1.0f / 16.0f;
#pragma unroll
  for (int n = 0; n < 4; ++n)
#pragma unroll
    for (int m = 0; m < 4; ++m) {
      f32x4 v = acc[n][m];
      v[0] *= s; v[1] *= s; v[2] *= s; v[3] *= s;
      size_t off = (size_t)(r0 + wr * 64 + m * 16 + l15) * CT +
                   (c0 + wc * 64 + n * 16 + l4 * 4);
      __builtin_nontemporal_store(v, reinterpret_cast<f32x4*>(O + off));
    }
}

// Correct-but-slow insurance path if ws_size is too small for the bf16 copies.
__global__ void __launch_bounds__(256) naive_kernel(const float* __restrict__ A,
                                                    const float* __restrict__ B,
                                                    float* __restrict__ O) {
  size_t i = (size_t)blockIdx.x * 256 + threadIdx.x;
  int col = (int)(i & (size_t)(CT - 1));
  int row = (int)(i >> 12);
  float s = 0.f;
  for (int k = 0; k < KT; ++k)
    s += A[(size_t)row * KT + k] * B[(size_t)k * CT + col];
  O[i] = s * (1.0f / 16.0f);
}

extern "C" void kernel_launch(void* const* d_in, const int* in_sizes, int n_in,
                              void* d_out, int out_size, void* d_ws, size_t ws_size,
                              hipStream_t stream) {
  const float* A = (const float*)d_in[0];
  const float* B = (const float*)d_in[1];
  float* O = (float*)d_out;
  const size_t needA = (size_t)MT * KT * sizeof(unsigned short);  // 16 MiB
  const size_t needB = (size_t)CT * KT * sizeof(unsigned short);  //  2 MiB
  if (ws_size >= needA + needB) {
    unsigned short* Abf = (unsigned short*)d_ws;
    unsigned short* Btw = (unsigned short*)((char*)d_ws + needA);
    cvtA_kernel<<<MT * KT / 8 / 256, 256, 0, stream>>>(A, Abf);
    cvtB_kernel<<<dim3(CT / 32, KT / 32), 1024, 0, stream>>>(B, Btw);
    gemm_kernel<<<(MT / 128) * (CT / 128), 256, 0, stream>>>(Abf, Btw, O);
  } else {
    naive_kernel<<<(unsigned)((size_t)MT * CT / 256), 256, 0, stream>>>(A, B, O);
  }
}

// Round 6
// 141.473 us; speedup vs baseline: 2.2607x; 1.0879x over previous
//
#include <hip/hip_runtime.h>
#include <hip/hip_bf16.h>

typedef __attribute__((ext_vector_type(8))) short short8;
typedef __attribute__((ext_vector_type(4))) float f32x4;

static constexpr int MT = 32768;  // rows
static constexpr int KT = 256;    // contraction
static constexpr int CT = 4096;   // classes

// round-to-nearest-even float -> bf16 bits
__device__ __forceinline__ unsigned short f2b(float f) {
  unsigned int b = __float_as_uint(f);
  b += 0x7FFFu + ((b >> 16) & 1u);
  return (unsigned short)(b >> 16);
}

__global__ void __launch_bounds__(256) cvtA_kernel(const float* __restrict__ A,
                                                   unsigned short* __restrict__ Abf) {
  int i = blockIdx.x * 256 + threadIdx.x;  // 8 floats per lane
  const float4 v0 = reinterpret_cast<const float4*>(A)[2 * i];
  const float4 v1 = reinterpret_cast<const float4*>(A)[2 * i + 1];
  short8 o;
  o[0] = (short)f2b(v0.x); o[1] = (short)f2b(v0.y);
  o[2] = (short)f2b(v0.z); o[3] = (short)f2b(v0.w);
  o[4] = (short)f2b(v1.x); o[5] = (short)f2b(v1.y);
  o[6] = (short)f2b(v1.z); o[7] = (short)f2b(v1.w);
  reinterpret_cast<short8*>(Abf)[i] = o;
}

// B [KT][CT] fp32 -> Bt [CT][KT] bf16 (LDS-tiled transpose)
__global__ void __launch_bounds__(1024) cvtB_kernel(const float* __restrict__ B,
                                                    unsigned short* __restrict__ Bt) {
  __shared__ unsigned short tile[32][33];
  int tx = threadIdx.x & 31, ty = threadIdx.x >> 5;
  int c0 = blockIdx.x * 32, k0 = blockIdx.y * 32;
  tile[ty][tx] = f2b(B[(size_t)(k0 + ty) * CT + c0 + tx]);
  __syncthreads();
  Bt[(size_t)(c0 + ty) * KT + k0 + tx] = tile[tx][ty];
}

__device__ __forceinline__ void gload16(const void* g, void* l) {
  __builtin_amdgcn_global_load_lds(
      (const __attribute__((address_space(1))) void*)g,
      (__attribute__((address_space(3))) void*)l, 16, 0, 0);
}

__global__ void __launch_bounds__(256) gemm_kernel(const unsigned short* __restrict__ Abf,
                                                   const unsigned short* __restrict__ Btw,
                                                   float* __restrict__ O) {
  constexpr int BM = 128, BN = 128, BK = 32;
  // 16896 B shared: K-loop aliases it as Al(8KB)+Bl(8KB); epilogue as
  // float eb[32][132] (stride 132 keeps 16B alignment + balanced bank quads).
  __shared__ __align__(16) char smem[32 * 132 * 4];
  unsigned short* Al = (unsigned short*)smem;
  unsigned short* Bl = (unsigned short*)(smem + 8192);
  float* eb = (float*)smem;

  int bid = blockIdx.x;
  // XCD-aware swizzle; 8192 % 8 == 0 so the simple form is bijective
  int wg = (bid & 7) * (8192 / 8) + (bid >> 3);
  int tc = wg & 31;   // 32 col tiles
  int tr = wg >> 5;   // 256 row tiles
  int r0 = tr * BM, c0 = tc * BN;

  int tid = threadIdx.x;
  int lane = tid & 63, wid = tid >> 6;
  int wr = wid >> 1, wc = wid & 1;      // 2x2 waves, each owns 64x64
  int l15 = lane & 15, l4 = lane >> 4;

  f32x4 acc[4][4] = {};  // acc[n][m], swapped-operand orientation

  const int rowA = tid >> 2;            // 0..63 within a 64-row half
  const int kofs = (tid & 3) * 8;       // ushort offset within 32-wide K slab

  for (int t = 0; t < KT / BK; ++t) {
    if (t) __syncthreads();
#pragma unroll
    for (int j = 0; j < 2; ++j) {
      gload16(Abf + (size_t)(r0 + j * 64 + rowA) * KT + t * BK + kofs,
              Al + j * 2048 + wid * 512);
      gload16(Btw + (size_t)(c0 + j * 64 + rowA) * KT + t * BK + kofs,
              Bl + j * 2048 + wid * 512);
    }
    __syncthreads();  // drains vmcnt before barrier

    short8 af[4], bf[4];
#pragma unroll
    for (int m = 0; m < 4; ++m)
      af[m] = *reinterpret_cast<const short8*>(Al + (wr * 64 + m * 16 + l15) * BK + l4 * 8);
#pragma unroll
    for (int n = 0; n < 4; ++n)
      bf[n] = *reinterpret_cast<const short8*>(Bl + (wc * 64 + n * 16 + l15) * BK + l4 * 8);
#pragma unroll
    for (int n = 0; n < 4; ++n)
#pragma unroll
      for (int m = 0; m < 4; ++m)
        // swapped operands: lane holds 4 consecutive C columns of one row
        acc[n][m] = __builtin_amdgcn_mfma_f32_16x16x32_bf16(bf[n], af[m], acc[n][m], 0, 0, 0);
  }

  // Epilogue via LDS: repack each m-group (32 rows x 128 cols) so NT stores
  // are 512B-contiguous per row (2 rows per wave instruction) instead of
  // 16 rows x 64B — DRAM page locality for the write stream.
  const float s = 1.0f / 16.0f;
#pragma unroll
  for (int m = 0; m < 4; ++m) {
    __syncthreads();  // smem free (last compute / previous store pass done)
#pragma unroll
    for (int n = 0; n < 4; ++n) {
      f32x4 v = acc[n][m];
      v[0] *= s; v[1] *= s; v[2] *= s; v[3] *= s;
      int lrow = wr * 16 + l15;                 // 0..31
      int col = wc * 64 + n * 16 + l4 * 4;      // 0..127
      *reinterpret_cast<f32x4*>(&eb[lrow * 132 + col]) = v;
    }
    __syncthreads();
#pragma unroll
    for (int p = 0; p < 4; ++p) {
      int r = p * 8 + (tid >> 5);               // 0..31
      int chunk = tid & 31;                     // 32 x 16B = one 512B row
      f32x4 v = *reinterpret_cast<const f32x4*>(&eb[r * 132 + chunk * 4]);
      int grow = (r >> 4) * 64 + m * 16 + (r & 15);
      __builtin_nontemporal_store(v, reinterpret_cast<f32x4*>(
          O + (size_t)(r0 + grow) * CT + c0 + chunk * 4));
    }
  }
}

// Correct-but-slow insurance path if ws_size is too small for the bf16 copies.
__global__ void __launch_bounds__(256) naive_kernel(const float* __restrict__ A,
                                                    const float* __restrict__ B,
                                                    float* __restrict__ O) {
  size_t i = (size_t)blockIdx.x * 256 + threadIdx.x;
  int col = (int)(i & (size_t)(CT - 1));
  int row = (int)(i >> 12);
  float s = 0.f;
  for (int k = 0; k < KT; ++k)
    s += A[(size_t)row * KT + k] * B[(size_t)k * CT + col];
  O[i] = s * (1.0f / 16.0f);
}

extern "C" void kernel_launch(void* const* d_in, const int* in_sizes, int n_in,
                              void* d_out, int out_size, void* d_ws, size_t ws_size,
                              hipStream_t stream) {
  const float* A = (const float*)d_in[0];
  const float* B = (const float*)d_in[1];
  float* O = (float*)d_out;
  const size_t needA = (size_t)MT * KT * sizeof(unsigned short);  // 16 MiB
  const size_t needB = (size_t)CT * KT * sizeof(unsigned short);  //  2 MiB
  if (ws_size >= needA + needB) {
    unsigned short* Abf = (unsigned short*)d_ws;
    unsigned short* Btw = (unsigned short*)((char*)d_ws + needA);
    cvtA_kernel<<<MT * KT / 8 / 256, 256, 0, stream>>>(A, Abf);
    cvtB_kernel<<<dim3(CT / 32, KT / 32), 1024, 0, stream>>>(B, Btw);
    gemm_kernel<<<(MT / 128) * (CT / 128), 256, 0, stream>>>(Abf, Btw, O);
  } else {
    naive_kernel<<<(unsigned)((size_t)MT * CT / 256), 256, 0, stream>>>(A, B, O);
  }
}